// Round 1
// baseline (2968.784 us; speedup 1.0000x reference)
//
#include <hip/hip_runtime.h>
#include <math.h>

#define T_LEN 65536
#define B_N   8
#define BT    (T_LEN * B_N)
#define L_N   16
#define RC    32
#define SC    64

// pass1 tiling
#define C1    1024
#define HALO  1020
#define BUFSZ 2048   // C1 + HALO = 2044, padded

__device__ __forceinline__ float fast_rcp(float x) { return __builtin_amdgcn_rcpf(x); }

// tanh(fp) * sigmoid(gp) with 2 exp + 1 rcp
__device__ __forceinline__ float gated_fn(float fp, float gp) {
    float E = __expf(2.f * fp);
    float F = __expf(gp);
    return (E - 1.f) * F * fast_rcp((E + 1.f) * (F + 1.f));
}

// ---------------------------------------------------------------------------
// prep: fold W_f/W_g (L,32,32,3) with W_in (L,32) and b_in (L,32)
// fw layout (floats): AF[L][3][32] @0, CF @1536, AG @3072, CG @4608  (6144 total)
// ---------------------------------------------------------------------------
__global__ __launch_bounds__(256) void prep_kernel(
    const float* __restrict__ W_f, const float* __restrict__ W_g,
    const float* __restrict__ W_in, const float* __restrict__ b_in,
    float* __restrict__ fw)
{
    int idx = blockIdx.x * 256 + threadIdx.x;      // 0 .. 1535
    if (idx >= L_N * 96) return;
    int i = idx / 96;
    int r = idx % 96;
    int k = r / 32;
    int c = r % 32;
    float af = 0.f, cf = 0.f, ag = 0.f, cg = 0.f;
    for (int cin = 0; cin < RC; ++cin) {
        float wf = W_f[((i * RC + c) * RC + cin) * 3 + k];
        float wg = W_g[((i * RC + c) * RC + cin) * 3 + k];
        float wi = W_in[i * RC + cin];
        float bi = b_in[i * RC + cin];
        af = fmaf(wf, wi, af);
        cf = fmaf(wf, bi, cf);
        ag = fmaf(wg, wi, ag);
        cg = fmaf(wg, bi, cg);
    }
    fw[0 * 1536 + idx] = af;
    fw[1 * 1536 + idx] = cf;
    fw[2 * 1536 + idx] = ag;
    fw[3 * 1536 + idx] = cg;
}

// ---------------------------------------------------------------------------
// pass1: compute scalar streams out_1 .. out_15 (inputs to layers 1..15).
// Each block: one (batch, chunk) of C1 timesteps + HALO halo, 15 layers in LDS.
// streams[i][b][t] = input stream of layer i+1.
// ---------------------------------------------------------------------------
__global__ __launch_bounds__(256) void pass1_kernel(
    const float* __restrict__ x, const float* __restrict__ fw,
    const float* __restrict__ b_f, const float* __restrict__ b_g,
    const float* __restrict__ W_o, const float* __restrict__ b_o,
    float* __restrict__ streams)
{
    __shared__ float buf[2][BUFSZ];
    __shared__ float laf[96], lcf[96], lag[96], lcg[96];
    __shared__ float lbf[32], lbg[32], lwo[32], lbo[1];

    int b     = blockIdx.x >> 6;          // 64 chunks per batch
    int chunk = blockIdx.x & 63;
    int t0    = chunk * C1;
    const float* xb = x + (size_t)b * T_LEN;

    for (int p = threadIdx.x; p < C1 + HALO; p += 256) {
        int t = t0 - HALO + p;
        buf[0][p] = (t >= 0) ? xb[t] : 0.f;
    }

    int cur = 0;
    int rem = 1020;                       // receptive field of layers i..15
    for (int i = 0; i < 15; ++i) {
        int d    = 1 << (i & 7);
        int remN = rem - 2 * d;           // rem_{i+1}
        __syncthreads();                  // prev compute done before lw overwrite
        for (int j = threadIdx.x; j < 96; j += 256) {
            laf[j] = fw[          i * 96 + j];
            lcf[j] = fw[1536 +    i * 96 + j];
            lag[j] = fw[3072 +    i * 96 + j];
            lcg[j] = fw[4608 +    i * 96 + j];
        }
        if (threadIdx.x < 32) {
            lbf[threadIdx.x] = b_f[i * 32 + threadIdx.x];
            lbg[threadIdx.x] = b_g[i * 32 + threadIdx.x];
            lwo[threadIdx.x] = W_o[i * 32 + threadIdx.x];
            if (threadIdx.x == 0) lbo[0] = b_o[i];
        }
        __syncthreads();

        int lo  = HALO - remN;
        int nxt = cur ^ 1;

        float s0[8], s1[8], s2[8], acc[8], m0v[8], m1v[8];
        bool  on[8];
        #pragma unroll
        for (int j = 0; j < 8; ++j) {
            int p = lo + (int)threadIdx.x + j * 256;
            int t = t0 - HALO + p;
            bool inr = (p < C1 + HALO);
            on[j]  = inr && (t >= 0);
            acc[j] = 0.f;
            if (inr) {
                s2[j] = buf[cur][p];
                s1[j] = buf[cur][p - d];
                s0[j] = buf[cur][p - 2 * d];
            } else { s2[j] = s1[j] = s0[j] = 0.f; }
            m1v[j] = (t - d     >= 0) ? 1.f : 0.f;
            m0v[j] = (t - 2 * d >= 0) ? 1.f : 0.f;
        }

        for (int c = 0; c < RC; ++c) {
            float af0 = laf[c], af1 = laf[32 + c], af2 = laf[64 + c];
            float ag0 = lag[c], ag1 = lag[32 + c], ag2 = lag[64 + c];
            float cf0 = lcf[c], cf1 = lcf[32 + c], cf2 = lcf[64 + c];
            float cg0 = lcg[c], cg1 = lcg[32 + c], cg2 = lcg[64 + c];
            float bfc = lbf[c], bgc = lbg[c], woc = lwo[c];
            #pragma unroll
            for (int j = 0; j < 8; ++j) {
                float fp = bfc + m0v[j] * cf0 + m1v[j] * cf1 + cf2;
                fp = fmaf(af0, s0[j], fmaf(af1, s1[j], fmaf(af2, s2[j], fp)));
                float gp = bgc + m0v[j] * cg0 + m1v[j] * cg1 + cg2;
                gp = fmaf(ag0, s0[j], fmaf(ag1, s1[j], fmaf(ag2, s2[j], gp)));
                acc[j] = fmaf(woc, gated_fn(fp, gp), acc[j]);
            }
        }

        #pragma unroll
        for (int j = 0; j < 8; ++j) {
            int p = lo + (int)threadIdx.x + j * 256;
            if (p < C1 + HALO) {
                int t = t0 - HALO + p;
                float outv = on[j] ? (s2[j] + lbo[0] + acc[j]) : 0.f;
                buf[nxt][p] = outv;
                if (p >= HALO)
                    streams[(size_t)i * BT + (size_t)b * T_LEN + t] = outv;
            }
        }
        cur = nxt;
        rem = remN;
    }
}

// ---------------------------------------------------------------------------
// pass2: per (b,t): recompute gated_i from stream taps, accumulate skip[64],
// apply head, write means / stds.
// ---------------------------------------------------------------------------
__global__ __launch_bounds__(256) void pass2_kernel(
    const float* __restrict__ x, const float* __restrict__ streams,
    const float* __restrict__ fw,
    const float* __restrict__ b_f, const float* __restrict__ b_g,
    const float* __restrict__ W_s, const float* __restrict__ b_s,
    const float* __restrict__ W_sk1, const float* __restrict__ b_sk1,
    const float* __restrict__ W_sk2, const float* __restrict__ b_sk2,
    float* __restrict__ out)
{
    __shared__ __align__(16) float sW[4096];   // per-layer W_s (2048) / head W_sk1 (4096)
    __shared__ float sB[64];
    __shared__ float laf[96], lcf[96], lag[96], lcg[96], lbf[32], lbg[32];
    __shared__ float sW2[128], sB2[2];

    int gt = blockIdx.x * 256 + threadIdx.x;   // 0 .. BT-1
    int b  = gt >> 16;
    int t  = gt & (T_LEN - 1);

    float skip[SC];
    #pragma unroll
    for (int s = 0; s < SC; ++s) skip[s] = 0.f;

    for (int i = 0; i < L_N; ++i) {
        __syncthreads();
        for (int j = threadIdx.x; j < 96; j += 256) {
            laf[j] = fw[          i * 96 + j];
            lcf[j] = fw[1536 +    i * 96 + j];
            lag[j] = fw[3072 +    i * 96 + j];
            lcg[j] = fw[4608 +    i * 96 + j];
        }
        if (threadIdx.x < 32) {
            lbf[threadIdx.x] = b_f[i * 32 + threadIdx.x];
            lbg[threadIdx.x] = b_g[i * 32 + threadIdx.x];
        }
        for (int j = threadIdx.x; j < SC * RC; j += 256)
            sW[j] = W_s[i * SC * RC + j];
        if (threadIdx.x < 64) sB[threadIdx.x] = b_s[i * 64 + threadIdx.x];
        __syncthreads();

        int d = 1 << (i & 7);
        const float* src = (i == 0) ? (x + (size_t)b * T_LEN)
                                    : (streams + (size_t)(i - 1) * BT + (size_t)b * T_LEN);
        float s2 = src[t];
        float s1 = 0.f, s0 = 0.f, m1v = 0.f, m0v = 0.f;
        if (t >= d)     { s1 = src[t - d];     m1v = 1.f; }
        if (t >= 2 * d) { s0 = src[t - 2 * d]; m0v = 1.f; }

        float gated[RC];
        #pragma unroll
        for (int c = 0; c < RC; ++c) {
            float fp = lbf[c] + m0v * lcf[c] + m1v * lcf[32 + c] + lcf[64 + c];
            fp = fmaf(laf[c], s0, fmaf(laf[32 + c], s1, fmaf(laf[64 + c], s2, fp)));
            float gp = lbg[c] + m0v * lcg[c] + m1v * lcg[32 + c] + lcg[64 + c];
            gp = fmaf(lag[c], s0, fmaf(lag[32 + c], s1, fmaf(lag[64 + c], s2, gp)));
            gated[c] = gated_fn(fp, gp);
        }

        #pragma unroll
        for (int s = 0; s < SC; ++s) {
            float a = skip[s] + sB[s];
            const float4* w4 = reinterpret_cast<const float4*>(&sW[s * RC]);
            #pragma unroll
            for (int c4 = 0; c4 < RC / 4; ++c4) {
                float4 w = w4[c4];
                a = fmaf(w.x, gated[4 * c4 + 0], a);
                a = fmaf(w.y, gated[4 * c4 + 1], a);
                a = fmaf(w.z, gated[4 * c4 + 2], a);
                a = fmaf(w.w, gated[4 * c4 + 3], a);
            }
            skip[s] = a;
        }
    }

    // head: skip -> relu(W_sk1 @ skip + b_sk1) -> W_sk2 @ . + b_sk2
    __syncthreads();
    for (int j = threadIdx.x; j < SC * SC; j += 256) sW[j] = W_sk1[j];
    if (threadIdx.x < 64)  sB[threadIdx.x]  = b_sk1[threadIdx.x];
    if (threadIdx.x < 128) sW2[threadIdx.x] = W_sk2[threadIdx.x];
    if (threadIdx.x < 2)   sB2[threadIdx.x] = b_sk2[threadIdx.x];
    __syncthreads();

    float a0 = sB2[0], a1 = sB2[1];
    for (int h = 0; h < SC; ++h) {
        float hv = sB[h];
        const float4* w4 = reinterpret_cast<const float4*>(&sW[h * SC]);
        #pragma unroll
        for (int c4 = 0; c4 < SC / 4; ++c4) {
            float4 w = w4[c4];
            hv = fmaf(w.x, skip[4 * c4 + 0], hv);
            hv = fmaf(w.y, skip[4 * c4 + 1], hv);
            hv = fmaf(w.z, skip[4 * c4 + 2], hv);
            hv = fmaf(w.w, skip[4 * c4 + 3], hv);
        }
        hv = fmaxf(hv, 0.f);
        a0 = fmaf(sW2[h],      hv, a0);
        a1 = fmaf(sW2[64 + h], hv, a1);
    }
    out[gt]      = a0;                       // means
    out[BT + gt] = __expf(0.5f * a1);        // stds
}

// ---------------------------------------------------------------------------
extern "C" void kernel_launch(void* const* d_in, const int* in_sizes, int n_in,
                              void* d_out, int out_size, void* d_ws, size_t ws_size,
                              hipStream_t stream) {
    const float* x     = (const float*)d_in[0];
    const float* W_in  = (const float*)d_in[1];
    const float* b_in  = (const float*)d_in[2];
    const float* W_f   = (const float*)d_in[3];
    const float* b_f   = (const float*)d_in[4];
    const float* W_g   = (const float*)d_in[5];
    const float* b_g   = (const float*)d_in[6];
    const float* W_s   = (const float*)d_in[7];
    const float* b_s   = (const float*)d_in[8];
    const float* W_o   = (const float*)d_in[9];
    const float* b_o   = (const float*)d_in[10];
    const float* W_sk1 = (const float*)d_in[11];
    const float* b_sk1 = (const float*)d_in[12];
    const float* W_sk2 = (const float*)d_in[13];
    const float* b_sk2 = (const float*)d_in[14];
    float* outp = (float*)d_out;

    float* streams = (float*)d_ws;                 // 15 * BT floats (30 MB)
    float* fw      = streams + (size_t)15 * BT;    // 6144 floats

    prep_kernel<<<6, 256, 0, stream>>>(W_f, W_g, W_in, b_in, fw);
    pass1_kernel<<<B_N * (T_LEN / C1), 256, 0, stream>>>(x, fw, b_f, b_g, W_o, b_o, streams);
    pass2_kernel<<<BT / 256, 256, 0, stream>>>(x, streams, fw, b_f, b_g, W_s, b_s,
                                               W_sk1, b_sk1, W_sk2, b_sk2, outp);
}

// Round 2
// 1314.958 us; speedup vs baseline: 2.2577x; 2.2577x over previous
//
#include <hip/hip_runtime.h>
#include <math.h>

#define T_LEN 65536
#define B_N   8
#define BT    (T_LEN * B_N)
#define L_N   16
#define RC    32
#define SC    64

// pass1 tiling
#define C1    1024
#define HALO  1020
#define BUFSZ 2048
#define NT1   512

// pass2 tiling
#define TS    128

// folded-weight array offsets (per layer, 12 arrays of 32)
#define A_AF0 0
#define A_AF1 32
#define A_AF2 64
#define A_CF0 96
#define A_CF1 128
#define A_BFC 160
#define A_AG0 192
#define A_AG1 224
#define A_AG2 256
#define A_CG0 288
#define A_CG1 320
#define A_BGC 352
#define FW_L  384
#define FW_TOT (L_N * FW_L)          // 6144
#define FW_BSUM FW_TOT               // +64

__device__ __forceinline__ float fast_rcp(float x) { return __builtin_amdgcn_rcpf(x); }

__device__ __forceinline__ float gated_fn(float fp, float gp) {
    float E = __expf(2.f * fp);
    float F = __expf(gp);
    return (E - 1.f) * F * fast_rcp((E + 1.f) * (F + 1.f));
}

// ---------------------------------------------------------------------------
// prep: fold W_f/W_g with W_in/b_in/b_f/b_g; also Bsum[s] = sum_i b_s[i][s].
// ---------------------------------------------------------------------------
__global__ __launch_bounds__(256) void prep_kernel(
    const float* __restrict__ W_f, const float* __restrict__ W_g,
    const float* __restrict__ W_in, const float* __restrict__ b_in,
    const float* __restrict__ b_f, const float* __restrict__ b_g,
    const float* __restrict__ b_s, float* __restrict__ fw)
{
    int idx = blockIdx.x * 256 + threadIdx.x;
    if (idx < L_N * RC) {
        int i = idx >> 5, c = idx & 31;
        float af[3] = {0,0,0}, cf[3] = {0,0,0}, ag[3] = {0,0,0}, cg[3] = {0,0,0};
        for (int cin = 0; cin < RC; ++cin) {
            float wi = W_in[i * RC + cin];
            float bi = b_in[i * RC + cin];
            #pragma unroll
            for (int k = 0; k < 3; ++k) {
                float wf = W_f[((i * RC + c) * RC + cin) * 3 + k];
                float wg = W_g[((i * RC + c) * RC + cin) * 3 + k];
                af[k] = fmaf(wf, wi, af[k]);
                cf[k] = fmaf(wf, bi, cf[k]);
                ag[k] = fmaf(wg, wi, ag[k]);
                cg[k] = fmaf(wg, bi, cg[k]);
            }
        }
        float* p = fw + i * FW_L;
        p[A_AF0 + c] = af[0]; p[A_AF1 + c] = af[1]; p[A_AF2 + c] = af[2];
        p[A_CF0 + c] = cf[0]; p[A_CF1 + c] = cf[1];
        p[A_BFC + c] = b_f[i * RC + c] + cf[2];
        p[A_AG0 + c] = ag[0]; p[A_AG1 + c] = ag[1]; p[A_AG2 + c] = ag[2];
        p[A_CG0 + c] = cg[0]; p[A_CG1 + c] = cg[1];
        p[A_BGC + c] = b_g[i * RC + c] + cg[2];
    } else if (idx < L_N * RC + SC) {
        int s = idx - L_N * RC;
        float acc = 0.f;
        for (int i = 0; i < L_N; ++i) acc += b_s[i * SC + s];
        fw[FW_BSUM + s] = acc;
    }
}

// ---------------------------------------------------------------------------
// pass1: scalar streams out_1..out_15 (inputs of layers 1..15). 512 threads.
// ---------------------------------------------------------------------------
__global__ __launch_bounds__(NT1) void pass1_kernel(
    const float* __restrict__ x, const float* __restrict__ fw,
    const float* __restrict__ W_o, const float* __restrict__ b_o,
    float* __restrict__ streams)
{
    __shared__ float buf[2][BUFSZ];
    __shared__ float sGW[FW_L];
    __shared__ float lwo[32], lbo[1];

    int b     = blockIdx.x >> 6;
    int chunk = blockIdx.x & 63;
    int t0    = chunk * C1;
    const float* xb = x + (size_t)b * T_LEN;
    int tid = threadIdx.x;

    for (int p = tid; p < C1 + HALO; p += NT1) {
        int t = t0 - HALO + p;
        buf[0][p] = (t >= 0) ? xb[t] : 0.f;
    }

    int cur = 0;
    int rem = HALO;
    for (int i = 0; i < 15; ++i) {
        int d    = 1 << (i & 7);
        int remN = rem - 2 * d;
        __syncthreads();
        if (tid < FW_L) sGW[tid] = fw[i * FW_L + tid];
        if (tid >= FW_L && tid < FW_L + 32) lwo[tid - FW_L] = W_o[i * 32 + (tid - FW_L)];
        if (tid == FW_L + 32) lbo[0] = b_o[i];
        __syncthreads();

        int lo  = HALO - remN;
        int nxt = cur ^ 1;

        float s0[4], s1[4], s2[4], acc[4], m0v[4], m1v[4];
        bool  on[4];
        #pragma unroll
        for (int j = 0; j < 4; ++j) {
            int p = lo + tid + j * NT1;
            int t = t0 - HALO + p;
            bool inr = (p < C1 + HALO);
            on[j]  = inr && (t >= 0);
            acc[j] = 0.f;
            if (inr) {
                s2[j] = buf[cur][p];
                s1[j] = buf[cur][p - d];
                s0[j] = buf[cur][p - 2 * d];
            } else { s2[j] = s1[j] = s0[j] = 0.f; }
            m1v[j] = (t - d     >= 0) ? 1.f : 0.f;
            m0v[j] = (t - 2 * d >= 0) ? 1.f : 0.f;
        }

        for (int c = 0; c < RC; ++c) {
            float af0 = sGW[A_AF0 + c], af1 = sGW[A_AF1 + c], af2 = sGW[A_AF2 + c];
            float cf0 = sGW[A_CF0 + c], cf1 = sGW[A_CF1 + c], bfc = sGW[A_BFC + c];
            float ag0 = sGW[A_AG0 + c], ag1 = sGW[A_AG1 + c], ag2 = sGW[A_AG2 + c];
            float cg0 = sGW[A_CG0 + c], cg1 = sGW[A_CG1 + c], bgc = sGW[A_BGC + c];
            float woc = lwo[c];
            #pragma unroll
            for (int j = 0; j < 4; ++j) {
                float fp = fmaf(m0v[j], cf0, fmaf(m1v[j], cf1, bfc));
                fp = fmaf(af0, s0[j], fmaf(af1, s1[j], fmaf(af2, s2[j], fp)));
                float gp = fmaf(m0v[j], cg0, fmaf(m1v[j], cg1, bgc));
                gp = fmaf(ag0, s0[j], fmaf(ag1, s1[j], fmaf(ag2, s2[j], gp)));
                acc[j] = fmaf(woc, gated_fn(fp, gp), acc[j]);
            }
        }

        #pragma unroll
        for (int j = 0; j < 4; ++j) {
            int p = lo + tid + j * NT1;
            if (p < C1 + HALO) {
                int t = t0 - HALO + p;
                float outv = on[j] ? (s2[j] + lbo[0] + acc[j]) : 0.f;
                buf[nxt][p] = outv;
                if (p >= HALO)
                    streams[(size_t)i * BT + (size_t)b * T_LEN + t] = outv;
            }
        }
        cur = nxt;
        rem = remN;
    }
}

// ---------------------------------------------------------------------------
// pass2: register-tiled GEMM. Block = 128 timesteps. Per layer: gate phase
// writes G[32][128] to LDS; GEMM phase accumulates C[8t][4s] per thread over
// K=32. Head = second GEMM (K=64) + shfl reduction.
// LDS carve (floats):
//   sGT  [0 .. 8192)      G rows (layer: 32x128) / skip rows (head: 64x128)
//   sW   [8192 .. 12288)  Wt (layer: 32x64) / W1t (head: 64x64)
//   sGW  [12288 .. 12672) per-layer folded gate weights (384)
//   sTap [12672 .. 13056) s2/s1/s0 taps (3x128)
//   sBsum[13056..13120) sB1[13120..13184) sW2[13184..13312) sB2[13312..13314)
// ---------------------------------------------------------------------------
#define SM_GT   0
#define SM_W    8192
#define SM_GW   12288
#define SM_TAP  12672
#define SM_BSUM 13056
#define SM_B1   13120
#define SM_W2   13184
#define SM_B2   13312
#define SM_TOT  13316

__global__ __launch_bounds__(256) void pass2_kernel(
    const float* __restrict__ x, const float* __restrict__ streams,
    const float* __restrict__ fw, const float* __restrict__ W_s,
    const float* __restrict__ W_sk1, const float* __restrict__ b_sk1,
    const float* __restrict__ W_sk2, const float* __restrict__ b_sk2,
    float* __restrict__ out)
{
    __shared__ float sm[SM_TOT];

    int tid   = threadIdx.x;
    int b     = blockIdx.x >> 9;          // 512 chunks per batch
    int chunk = blockIdx.x & 511;
    int t0    = chunk * TS;

    // one-time small staging
    if (tid < 64) {
        sm[SM_BSUM + tid] = fw[FW_BSUM + tid];
        sm[SM_B1 + tid]   = b_sk1[tid];
    }
    if (tid < 128) sm[SM_W2 + tid] = W_sk2[tid];
    if (tid < 2)   sm[SM_B2 + tid] = b_sk2[tid];

    int tg = tid >> 4;                    // 0..15 : t-group (8 t each)
    int sg = tid & 15;                    // 0..15 : s-group (4 s each)
    int tl = tid >> 1;                    // 0..127: gate-phase timestep
    int h  = tid & 1;                     // gate-phase channel half

    float C[8][4];
    #pragma unroll
    for (int a = 0; a < 8; ++a)
        #pragma unroll
        for (int c = 0; c < 4; ++c) C[a][c] = 0.f;

    for (int i = 0; i < L_N; ++i) {
        int d = 1 << (i & 7);
        const float* src = (i == 0) ? (x + (size_t)b * T_LEN)
                                    : (streams + (size_t)(i - 1) * BT + (size_t)b * T_LEN);
        __syncthreads();   // prev GEMM done with sW
        // stage gate weights
        if (tid < 128) {
            sm[SM_GW + tid]       = fw[i * FW_L + tid];
            sm[SM_GW + 128 + tid] = fw[i * FW_L + 128 + tid];
            sm[SM_GW + 256 + tid] = fw[i * FW_L + 256 + tid];
        }
        // stage W_s[i] transposed: [s][c] -> sW[c*64+s]
        for (int j = tid; j < SC * RC; j += 256) {
            int s = j >> 5, c = j & 31;
            sm[SM_W + c * 64 + s] = W_s[i * SC * RC + j];
        }
        // stage taps
        for (int j = tid; j < 3 * TS; j += 256) {
            int a = j >> 7, p = j & (TS - 1);
            int t = t0 + p - a * d;
            sm[SM_TAP + j] = (t >= 0) ? src[t] : 0.f;
        }
        __syncthreads();

        // ---- gate phase: this thread computes 16 channels at timestep tl ----
        {
            float s2v = sm[SM_TAP + tl];
            float s1v = sm[SM_TAP + TS + tl];
            float s0v = sm[SM_TAP + 2 * TS + tl];
            int t = t0 + tl;
            float m1 = (t >= d)     ? 1.f : 0.f;
            float m0 = (t >= 2 * d) ? 1.f : 0.f;
            #pragma unroll
            for (int cg = 0; cg < 4; ++cg) {
                int c0 = h * 16 + cg * 4;
                const float* gw = sm + SM_GW;
                float4 af0 = *(const float4*)(gw + A_AF0 + c0);
                float4 af1 = *(const float4*)(gw + A_AF1 + c0);
                float4 af2 = *(const float4*)(gw + A_AF2 + c0);
                float4 cf0 = *(const float4*)(gw + A_CF0 + c0);
                float4 cf1 = *(const float4*)(gw + A_CF1 + c0);
                float4 bfc = *(const float4*)(gw + A_BFC + c0);
                float4 ag0 = *(const float4*)(gw + A_AG0 + c0);
                float4 ag1 = *(const float4*)(gw + A_AG1 + c0);
                float4 ag2 = *(const float4*)(gw + A_AG2 + c0);
                float4 cg0 = *(const float4*)(gw + A_CG0 + c0);
                float4 cg1 = *(const float4*)(gw + A_CG1 + c0);
                float4 bgc = *(const float4*)(gw + A_BGC + c0);
                float fpv[4], gpv[4];
                #define GATE1(cc, F) do { \
                    float fp = fmaf(m0, cf0.F, fmaf(m1, cf1.F, bfc.F)); \
                    fp = fmaf(af0.F, s0v, fmaf(af1.F, s1v, fmaf(af2.F, s2v, fp))); \
                    float gp = fmaf(m0, cg0.F, fmaf(m1, cg1.F, bgc.F)); \
                    gp = fmaf(ag0.F, s0v, fmaf(ag1.F, s1v, fmaf(ag2.F, s2v, gp))); \
                    fpv[cc] = fp; gpv[cc] = gp; } while (0)
                GATE1(0, x); GATE1(1, y); GATE1(2, z); GATE1(3, w);
                #undef GATE1
                #pragma unroll
                for (int cc = 0; cc < 4; ++cc)
                    sm[SM_GT + (c0 + cc) * TS + tl] = gated_fn(fpv[cc], gpv[cc]);
            }
        }
        __syncthreads();

        // ---- GEMM phase: C[8t][4s] += G[k][t] * Wt[k][s], K=32 ----
        {
            const float* gb = sm + SM_GT + tg * 8;
            const float* wb = sm + SM_W + sg * 4;
            #pragma unroll
            for (int k = 0; k < RC; ++k) {
                float4 g0 = *(const float4*)(gb + k * TS);
                float4 g1 = *(const float4*)(gb + k * TS + 4);
                float4 w  = *(const float4*)(wb + k * 64);
                float g[8] = {g0.x, g0.y, g0.z, g0.w, g1.x, g1.y, g1.z, g1.w};
                float wv[4] = {w.x, w.y, w.z, w.w};
                #pragma unroll
                for (int a = 0; a < 8; ++a)
                    #pragma unroll
                    for (int c = 0; c < 4; ++c)
                        C[a][c] = fmaf(g[a], wv[c], C[a][c]);
            }
        }
    }

    // ---- head ----
    __syncthreads();
    // write skip (+Bsum) transposed to sGT: sSkip[s][t], 64x128
    #pragma unroll
    for (int ss = 0; ss < 4; ++ss) {
        int s = sg * 4 + ss;
        float bs = sm[SM_BSUM + s];
        float4 w0 = make_float4(C[0][ss] + bs, C[1][ss] + bs, C[2][ss] + bs, C[3][ss] + bs);
        float4 w1 = make_float4(C[4][ss] + bs, C[5][ss] + bs, C[6][ss] + bs, C[7][ss] + bs);
        *(float4*)(sm + SM_GT + s * TS + tg * 8)     = w0;
        *(float4*)(sm + SM_GT + s * TS + tg * 8 + 4) = w1;
    }
    // stage W_sk1 transposed: [o][s] -> sW[s*64+o]
    for (int j = tid; j < SC * SC; j += 256) {
        int o = j >> 6, s = j & 63;
        sm[SM_W + s * 64 + o] = W_sk1[j];
    }
    __syncthreads();

    // head GEMM: H[8t][4o] = relu(sum_s skip[t][s] * W1[o][s] + b1[o])
    float H[8][4];
    #pragma unroll
    for (int a = 0; a < 8; ++a)
        #pragma unroll
        for (int c = 0; c < 4; ++c) H[a][c] = 0.f;
    {
        const float* gb = sm + SM_GT + tg * 8;
        const float* wb = sm + SM_W + sg * 4;   // sg doubles as o-group
        #pragma unroll
        for (int k = 0; k < SC; ++k) {
            float4 g0 = *(const float4*)(gb + k * TS);
            float4 g1 = *(const float4*)(gb + k * TS + 4);
            float4 w  = *(const float4*)(wb + k * 64);
            float g[8] = {g0.x, g0.y, g0.z, g0.w, g1.x, g1.y, g1.z, g1.w};
            float wv[4] = {w.x, w.y, w.z, w.w};
            #pragma unroll
            for (int a = 0; a < 8; ++a)
                #pragma unroll
                for (int c = 0; c < 4; ++c)
                    H[a][c] = fmaf(g[a], wv[c], H[a][c]);
        }
    }
    float p0[8], p1[8];
    #pragma unroll
    for (int a = 0; a < 8; ++a) { p0[a] = 0.f; p1[a] = 0.f; }
    #pragma unroll
    for (int c = 0; c < 4; ++c) {
        int o = sg * 4 + c;
        float w20 = sm[SM_W2 + o];
        float w21 = sm[SM_W2 + 64 + o];
        float b1v = sm[SM_B1 + o];
        #pragma unroll
        for (int a = 0; a < 8; ++a) {
            float hv = fmaxf(H[a][c] + b1v, 0.f);
            p0[a] = fmaf(w20, hv, p0[a]);
            p1[a] = fmaf(w21, hv, p1[a]);
        }
    }
    // reduce across the 16 o-groups (lanes differing in bits 0..3)
    #pragma unroll
    for (int m = 1; m <= 8; m <<= 1) {
        #pragma unroll
        for (int a = 0; a < 8; ++a) {
            p0[a] += __shfl_xor(p0[a], m);
            p1[a] += __shfl_xor(p1[a], m);
        }
    }
    if (sg == 0) {
        float b20 = sm[SM_B2], b21 = sm[SM_B2 + 1];
        #pragma unroll
        for (int a = 0; a < 8; ++a) {
            int t = t0 + tg * 8 + a;
            size_t gi = (size_t)b * T_LEN + t;
            out[gi]      = p0[a] + b20;
            out[BT + gi] = __expf(0.5f * (p1[a] + b21));
        }
    }
}

// ---------------------------------------------------------------------------
extern "C" void kernel_launch(void* const* d_in, const int* in_sizes, int n_in,
                              void* d_out, int out_size, void* d_ws, size_t ws_size,
                              hipStream_t stream) {
    const float* x     = (const float*)d_in[0];
    const float* W_in  = (const float*)d_in[1];
    const float* b_in  = (const float*)d_in[2];
    const float* W_f   = (const float*)d_in[3];
    const float* b_f   = (const float*)d_in[4];
    const float* W_g   = (const float*)d_in[5];
    const float* b_g   = (const float*)d_in[6];
    const float* W_s   = (const float*)d_in[7];
    const float* b_s   = (const float*)d_in[8];
    const float* W_o   = (const float*)d_in[9];
    const float* b_o   = (const float*)d_in[10];
    const float* W_sk1 = (const float*)d_in[11];
    const float* b_sk1 = (const float*)d_in[12];
    const float* W_sk2 = (const float*)d_in[13];
    const float* b_sk2 = (const float*)d_in[14];
    float* outp = (float*)d_out;

    float* streams = (float*)d_ws;                 // 15*BT floats (30 MB)
    float* fw      = streams + (size_t)15 * BT;    // 6208 floats

    prep_kernel<<<3, 256, 0, stream>>>(W_f, W_g, W_in, b_in, b_f, b_g, b_s, fw);
    pass1_kernel<<<B_N * (T_LEN / C1), NT1, 0, stream>>>(x, fw, W_o, b_o, streams);
    pass2_kernel<<<B_N * (T_LEN / TS), 256, 0, stream>>>(x, streams, fw, W_s,
                                                         W_sk1, b_sk1, W_sk2, b_sk2, outp);
}

// Round 3
// 1008.262 us; speedup vs baseline: 2.9445x; 1.3042x over previous
//
#include <hip/hip_runtime.h>
#include <math.h>

#define T_LEN 65536
#define B_N   8
#define BT    (T_LEN * B_N)
#define L_N   16
#define RC    32
#define SC    64

// pass1 tiling
#define C1    1024
#define HALO  1020
#define BUFSZ 2048
#define NT1   512

// pass2 tiling
#define TS    128

// folded-weight array offsets (per layer, 12 arrays of 32)
#define A_AF0 0
#define A_AF1 32
#define A_AF2 64
#define A_CF0 96
#define A_CF1 128
#define A_BFC 160
#define A_AG0 192
#define A_AG1 224
#define A_AG2 256
#define A_CG0 288
#define A_CG1 320
#define A_BGC 352
#define FW_L  384
#define FW_TOT (L_N * FW_L)          // 6144
#define FW_BSUM FW_TOT               // +64
#define FW_WST  (FW_BSUM + 64)       // +16*2048 = 32768 : W_s transposed [i][c][s]
#define FW_W1T  (FW_WST + L_N * RC * SC)  // +4096 : W_sk1 transposed [s][o]
#define FW_ALL  (FW_W1T + SC * SC)

typedef float v2f __attribute__((ext_vector_type(2)));

__device__ __forceinline__ v2f sp(float s) { return (v2f){s, s}; }
__device__ __forceinline__ v2f vlo(float4 v) { return (v2f){v.x, v.y}; }
__device__ __forceinline__ v2f vhi(float4 v) { return (v2f){v.z, v.w}; }

__device__ __forceinline__ float fast_rcp(float x) { return __builtin_amdgcn_rcpf(x); }

__device__ __forceinline__ float gated_fn(float fp, float gp) {
    float E = __expf(2.f * fp);
    float F = __expf(gp);
    return (E - 1.f) * F * fast_rcp((E + 1.f) * (F + 1.f));
}

// ---------------------------------------------------------------------------
// prep: fold gate weights; Bsum; pre-transpose W_s and W_sk1 (kills the
// 32-way LDS bank conflicts the in-pass2 transposes caused).
// ---------------------------------------------------------------------------
__global__ __launch_bounds__(256) void prep_kernel(
    const float* __restrict__ W_f, const float* __restrict__ W_g,
    const float* __restrict__ W_in, const float* __restrict__ b_in,
    const float* __restrict__ b_f, const float* __restrict__ b_g,
    const float* __restrict__ b_s, const float* __restrict__ W_s,
    const float* __restrict__ W_sk1, float* __restrict__ fw)
{
    int idx = blockIdx.x * 256 + threadIdx.x;
    if (idx < L_N * RC) {
        int i = idx >> 5, c = idx & 31;
        float af[3] = {0,0,0}, cf[3] = {0,0,0}, ag[3] = {0,0,0}, cg[3] = {0,0,0};
        for (int cin = 0; cin < RC; ++cin) {
            float wi = W_in[i * RC + cin];
            float bi = b_in[i * RC + cin];
            #pragma unroll
            for (int k = 0; k < 3; ++k) {
                float wf = W_f[((i * RC + c) * RC + cin) * 3 + k];
                float wg = W_g[((i * RC + c) * RC + cin) * 3 + k];
                af[k] = fmaf(wf, wi, af[k]);
                cf[k] = fmaf(wf, bi, cf[k]);
                ag[k] = fmaf(wg, wi, ag[k]);
                cg[k] = fmaf(wg, bi, cg[k]);
            }
        }
        float* p = fw + i * FW_L;
        p[A_AF0 + c] = af[0]; p[A_AF1 + c] = af[1]; p[A_AF2 + c] = af[2];
        p[A_CF0 + c] = cf[0]; p[A_CF1 + c] = cf[1];
        p[A_BFC + c] = b_f[i * RC + c] + cf[2];
        p[A_AG0 + c] = ag[0]; p[A_AG1 + c] = ag[1]; p[A_AG2 + c] = ag[2];
        p[A_CG0 + c] = cg[0]; p[A_CG1 + c] = cg[1];
        p[A_BGC + c] = b_g[i * RC + c] + cg[2];
    } else if (idx < L_N * RC + SC) {
        int s = idx - L_N * RC;
        float acc = 0.f;
        for (int i = 0; i < L_N; ++i) acc += b_s[i * SC + s];
        fw[FW_BSUM + s] = acc;
    } else if (idx < 576 + L_N * RC * SC) {
        int j = idx - 576;
        int i = j >> 11, r = j & 2047;
        int c = r >> 6, s = r & 63;
        fw[FW_WST + i * 2048 + c * 64 + s] = W_s[((size_t)i * SC + s) * RC + c];
    } else if (idx < 576 + L_N * RC * SC + SC * SC) {
        int j = idx - (576 + L_N * RC * SC);
        int s = j >> 6, o = j & 63;
        fw[FW_W1T + s * 64 + o] = W_sk1[o * SC + s];
    }
}

// ---------------------------------------------------------------------------
// pass1: scalar streams out_1..out_15 (inputs of layers 1..15). 512 threads.
// ---------------------------------------------------------------------------
__global__ __launch_bounds__(NT1) void pass1_kernel(
    const float* __restrict__ x, const float* __restrict__ fw,
    const float* __restrict__ W_o, const float* __restrict__ b_o,
    float* __restrict__ streams)
{
    __shared__ float buf[2][BUFSZ];
    __shared__ float sGW[FW_L];
    __shared__ float lwo[32], lbo[1];

    int b     = blockIdx.x >> 6;
    int chunk = blockIdx.x & 63;
    int t0    = chunk * C1;
    const float* xb = x + (size_t)b * T_LEN;
    int tid = threadIdx.x;

    for (int p = tid; p < C1 + HALO; p += NT1) {
        int t = t0 - HALO + p;
        buf[0][p] = (t >= 0) ? xb[t] : 0.f;
    }

    int cur = 0;
    int rem = HALO;
    for (int i = 0; i < 15; ++i) {
        int d    = 1 << (i & 7);
        int remN = rem - 2 * d;
        __syncthreads();
        if (tid < FW_L) sGW[tid] = fw[i * FW_L + tid];
        if (tid >= FW_L && tid < FW_L + 32) lwo[tid - FW_L] = W_o[i * 32 + (tid - FW_L)];
        if (tid == FW_L + 32) lbo[0] = b_o[i];
        __syncthreads();

        int lo  = HALO - remN;
        int nxt = cur ^ 1;

        v2f s0p[2], s1p[2], s2p[2], accp[2], m0p[2], m1p[2];
        bool on[4];
        #pragma unroll
        for (int j = 0; j < 4; ++j) {
            int p = lo + tid + j * NT1;
            int t = t0 - HALO + p;
            bool inr = (p < C1 + HALO);
            on[j]  = inr && (t >= 0);
            int jp = j >> 1, e = j & 1;
            float v2 = 0.f, v1 = 0.f, v0 = 0.f;
            if (inr) {
                v2 = buf[cur][p];
                v1 = buf[cur][p - d];
                v0 = buf[cur][p - 2 * d];
            }
            if (e == 0) {
                s2p[jp].x = v2; s1p[jp].x = v1; s0p[jp].x = v0;
                accp[jp].x = 0.f;
                m1p[jp].x = (t - d     >= 0) ? 1.f : 0.f;
                m0p[jp].x = (t - 2 * d >= 0) ? 1.f : 0.f;
            } else {
                s2p[jp].y = v2; s1p[jp].y = v1; s0p[jp].y = v0;
                accp[jp].y = 0.f;
                m1p[jp].y = (t - d     >= 0) ? 1.f : 0.f;
                m0p[jp].y = (t - 2 * d >= 0) ? 1.f : 0.f;
            }
        }

        for (int c = 0; c < RC; ++c) {
            float af0 = sGW[A_AF0 + c], af1 = sGW[A_AF1 + c], af2 = sGW[A_AF2 + c];
            float cf0 = sGW[A_CF0 + c], cf1 = sGW[A_CF1 + c], bfc = sGW[A_BFC + c];
            float ag0 = sGW[A_AG0 + c], ag1 = sGW[A_AG1 + c], ag2 = sGW[A_AG2 + c];
            float cg0 = sGW[A_CG0 + c], cg1 = sGW[A_CG1 + c], bgc = sGW[A_BGC + c];
            float woc = lwo[c];
            #pragma unroll
            for (int jp = 0; jp < 2; ++jp) {
                v2f fp = sp(bfc) + m0p[jp] * sp(cf0) + m1p[jp] * sp(cf1);
                fp = fp + s0p[jp] * sp(af0) + s1p[jp] * sp(af1) + s2p[jp] * sp(af2);
                v2f gp = sp(bgc) + m0p[jp] * sp(cg0) + m1p[jp] * sp(cg1);
                gp = gp + s0p[jp] * sp(ag0) + s1p[jp] * sp(ag1) + s2p[jp] * sp(ag2);
                v2f g;
                g.x = gated_fn(fp.x, gp.x);
                g.y = gated_fn(fp.y, gp.y);
                accp[jp] = accp[jp] + g * sp(woc);
            }
        }

        float s2a[4]  = {s2p[0].x, s2p[0].y, s2p[1].x, s2p[1].y};
        float acca[4] = {accp[0].x, accp[0].y, accp[1].x, accp[1].y};
        #pragma unroll
        for (int j = 0; j < 4; ++j) {
            int p = lo + tid + j * NT1;
            if (p < C1 + HALO) {
                int t = t0 - HALO + p;
                float outv = on[j] ? (s2a[j] + lbo[0] + acca[j]) : 0.f;
                buf[nxt][p] = outv;
                if (p >= HALO)
                    streams[(size_t)i * BT + (size_t)b * T_LEN + t] = outv;
            }
        }
        cur = nxt;
        rem = remN;
    }
}

// ---------------------------------------------------------------------------
// pass2: register-tiled GEMM with packed-f32 accumulation.
// LDS carve (floats): see offsets below.
// ---------------------------------------------------------------------------
#define SM_GT   0
#define SM_W    8192
#define SM_GW   12288
#define SM_TAP  12672
#define SM_BSUM 13056
#define SM_B1   13120
#define SM_W2   13184
#define SM_B2   13312
#define SM_TOT  13316

__global__ __launch_bounds__(256) void pass2_kernel(
    const float* __restrict__ x, const float* __restrict__ streams,
    const float* __restrict__ fw,
    const float* __restrict__ b_sk1,
    const float* __restrict__ W_sk2, const float* __restrict__ b_sk2,
    float* __restrict__ out)
{
    __shared__ __align__(16) float sm[SM_TOT];

    int tid   = threadIdx.x;
    int b     = blockIdx.x >> 9;
    int chunk = blockIdx.x & 511;
    int t0    = chunk * TS;

    if (tid < 64) {
        sm[SM_BSUM + tid] = fw[FW_BSUM + tid];
        sm[SM_B1 + tid]   = b_sk1[tid];
    }
    if (tid < 128) sm[SM_W2 + tid] = W_sk2[tid];
    if (tid < 2)   sm[SM_B2 + tid] = b_sk2[tid];

    int tg = tid >> 4;                    // 0..15 : t-group (8 t each)
    int sg = tid & 15;                    // 0..15 : s-group (4 s each)
    int tl = tid >> 1;                    // 0..127: gate-phase timestep
    int h  = tid & 1;                     // gate-phase channel half

    v2f C2[4][4];
    #pragma unroll
    for (int a = 0; a < 4; ++a)
        #pragma unroll
        for (int c = 0; c < 4; ++c) C2[a][c] = sp(0.f);

    for (int i = 0; i < L_N; ++i) {
        int d = 1 << (i & 7);
        const float* src = (i == 0) ? (x + (size_t)b * T_LEN)
                                    : (streams + (size_t)(i - 1) * BT + (size_t)b * T_LEN);
        __syncthreads();   // prev GEMM done with sW
        // stage gate weights
        if (tid < 128) {
            sm[SM_GW + tid]       = fw[i * FW_L + tid];
            sm[SM_GW + 128 + tid] = fw[i * FW_L + 128 + tid];
            sm[SM_GW + 256 + tid] = fw[i * FW_L + 256 + tid];
        }
        // stage pre-transposed W_s[i]: straight coalesced copy, no conflicts
        {
            const float* wsrc = fw + FW_WST + i * 2048;
            for (int j = tid; j < SC * RC; j += 256)
                sm[SM_W + j] = wsrc[j];
        }
        // stage taps
        for (int j = tid; j < 3 * TS; j += 256) {
            int a = j >> 7, p = j & (TS - 1);
            int t = t0 + p - a * d;
            sm[SM_TAP + j] = (t >= 0) ? src[t] : 0.f;
        }
        __syncthreads();

        // ---- gate phase: this thread computes 16 channels at timestep tl ----
        {
            float s2v = sm[SM_TAP + tl];
            float s1v = sm[SM_TAP + TS + tl];
            float s0v = sm[SM_TAP + 2 * TS + tl];
            int t = t0 + tl;
            float m1 = (t >= d)     ? 1.f : 0.f;
            float m0 = (t >= 2 * d) ? 1.f : 0.f;
            #pragma unroll
            for (int cg = 0; cg < 4; ++cg) {
                int c0 = h * 16 + cg * 4;
                const float* gw = sm + SM_GW;
                float4 af0 = *(const float4*)(gw + A_AF0 + c0);
                float4 af1 = *(const float4*)(gw + A_AF1 + c0);
                float4 af2 = *(const float4*)(gw + A_AF2 + c0);
                float4 cf0 = *(const float4*)(gw + A_CF0 + c0);
                float4 cf1 = *(const float4*)(gw + A_CF1 + c0);
                float4 bfc = *(const float4*)(gw + A_BFC + c0);
                float4 ag0 = *(const float4*)(gw + A_AG0 + c0);
                float4 ag1 = *(const float4*)(gw + A_AG1 + c0);
                float4 ag2 = *(const float4*)(gw + A_AG2 + c0);
                float4 cg0 = *(const float4*)(gw + A_CG0 + c0);
                float4 cg1 = *(const float4*)(gw + A_CG1 + c0);
                float4 bgc = *(const float4*)(gw + A_BGC + c0);
                // pair (c0, c0+1)
                v2f fpA = vlo(bfc) + sp(m0) * vlo(cf0) + sp(m1) * vlo(cf1);
                fpA = fpA + sp(s0v) * vlo(af0) + sp(s1v) * vlo(af1) + sp(s2v) * vlo(af2);
                v2f gpA = vlo(bgc) + sp(m0) * vlo(cg0) + sp(m1) * vlo(cg1);
                gpA = gpA + sp(s0v) * vlo(ag0) + sp(s1v) * vlo(ag1) + sp(s2v) * vlo(ag2);
                // pair (c0+2, c0+3)
                v2f fpB = vhi(bfc) + sp(m0) * vhi(cf0) + sp(m1) * vhi(cf1);
                fpB = fpB + sp(s0v) * vhi(af0) + sp(s1v) * vhi(af1) + sp(s2v) * vhi(af2);
                v2f gpB = vhi(bgc) + sp(m0) * vhi(cg0) + sp(m1) * vhi(cg1);
                gpB = gpB + sp(s0v) * vhi(ag0) + sp(s1v) * vhi(ag1) + sp(s2v) * vhi(ag2);
                sm[SM_GT + (c0 + 0) * TS + tl] = gated_fn(fpA.x, gpA.x);
                sm[SM_GT + (c0 + 1) * TS + tl] = gated_fn(fpA.y, gpA.y);
                sm[SM_GT + (c0 + 2) * TS + tl] = gated_fn(fpB.x, gpB.x);
                sm[SM_GT + (c0 + 3) * TS + tl] = gated_fn(fpB.y, gpB.y);
            }
        }
        __syncthreads();

        // ---- GEMM phase: C[8t][4s] += G[k][t] * Wt[k][s], K=32, packed ----
        {
            const float* gb = sm + SM_GT + tg * 8;
            const float* wb = sm + SM_W + sg * 4;
            #pragma unroll
            for (int k = 0; k < RC; ++k) {
                float4 g0 = *(const float4*)(gb + k * TS);
                float4 g1 = *(const float4*)(gb + k * TS + 4);
                float4 w  = *(const float4*)(wb + k * 64);
                v2f gp[4] = {vlo(g0), vhi(g0), vlo(g1), vhi(g1)};
                float wv[4] = {w.x, w.y, w.z, w.w};
                #pragma unroll
                for (int a = 0; a < 4; ++a)
                    #pragma unroll
                    for (int c = 0; c < 4; ++c)
                        C2[a][c] = C2[a][c] + gp[a] * sp(wv[c]);
            }
        }
    }

    // ---- head ----
    __syncthreads();
    // write skip (+Bsum) transposed to sGT: sSkip[s][t], 64x128
    #pragma unroll
    for (int ss = 0; ss < 4; ++ss) {
        int s = sg * 4 + ss;
        float bs = sm[SM_BSUM + s];
        float4 w0 = make_float4(C2[0][ss].x + bs, C2[0][ss].y + bs,
                                C2[1][ss].x + bs, C2[1][ss].y + bs);
        float4 w1 = make_float4(C2[2][ss].x + bs, C2[2][ss].y + bs,
                                C2[3][ss].x + bs, C2[3][ss].y + bs);
        *(float4*)(sm + SM_GT + s * TS + tg * 8)     = w0;
        *(float4*)(sm + SM_GT + s * TS + tg * 8 + 4) = w1;
    }
    // stage pre-transposed W_sk1: coalesced copy
    {
        const float* w1 = fw + FW_W1T;
        for (int j = tid; j < SC * SC; j += 256)
            sm[SM_W + j] = w1[j];
    }
    __syncthreads();

    // head GEMM: H[8t][4o] = sum_s skip[t][s] * W1t[s][o], packed
    v2f H2[4][4];
    #pragma unroll
    for (int a = 0; a < 4; ++a)
        #pragma unroll
        for (int c = 0; c < 4; ++c) H2[a][c] = sp(0.f);
    {
        const float* gb = sm + SM_GT + tg * 8;
        const float* wb = sm + SM_W + sg * 4;   // sg doubles as o-group
        #pragma unroll
        for (int k = 0; k < SC; ++k) {
            float4 g0 = *(const float4*)(gb + k * TS);
            float4 g1 = *(const float4*)(gb + k * TS + 4);
            float4 w  = *(const float4*)(wb + k * 64);
            v2f gp[4] = {vlo(g0), vhi(g0), vlo(g1), vhi(g1)};
            float wv[4] = {w.x, w.y, w.z, w.w};
            #pragma unroll
            for (int a = 0; a < 4; ++a)
                #pragma unroll
                for (int c = 0; c < 4; ++c)
                    H2[a][c] = H2[a][c] + gp[a] * sp(wv[c]);
        }
    }
    v2f p0p[4], p1p[4];
    #pragma unroll
    for (int a = 0; a < 4; ++a) { p0p[a] = sp(0.f); p1p[a] = sp(0.f); }
    #pragma unroll
    for (int c = 0; c < 4; ++c) {
        int o = sg * 4 + c;
        float w20 = sm[SM_W2 + o];
        float w21 = sm[SM_W2 + 64 + o];
        float b1v = sm[SM_B1 + o];
        #pragma unroll
        for (int a = 0; a < 4; ++a) {
            v2f hv = H2[a][c] + sp(b1v);
            hv.x = fmaxf(hv.x, 0.f);
            hv.y = fmaxf(hv.y, 0.f);
            p0p[a] = p0p[a] + hv * sp(w20);
            p1p[a] = p1p[a] + hv * sp(w21);
        }
    }
    // reduce across the 16 o-groups (lanes differing in bits 0..3)
    #pragma unroll
    for (int m = 1; m <= 8; m <<= 1) {
        #pragma unroll
        for (int a = 0; a < 4; ++a) {
            p0p[a].x += __shfl_xor(p0p[a].x, m);
            p0p[a].y += __shfl_xor(p0p[a].y, m);
            p1p[a].x += __shfl_xor(p1p[a].x, m);
            p1p[a].y += __shfl_xor(p1p[a].y, m);
        }
    }
    if (sg == 0) {
        float b20 = sm[SM_B2], b21 = sm[SM_B2 + 1];
        #pragma unroll
        for (int a = 0; a < 4; ++a) {
            int t = t0 + tg * 8 + 2 * a;
            size_t gi = (size_t)b * T_LEN + t;
            out[gi]          = p0p[a].x + b20;
            out[gi + 1]      = p0p[a].y + b20;
            out[BT + gi]     = __expf(0.5f * (p1p[a].x + b21));
            out[BT + gi + 1] = __expf(0.5f * (p1p[a].y + b21));
        }
    }
}

// ---------------------------------------------------------------------------
extern "C" void kernel_launch(void* const* d_in, const int* in_sizes, int n_in,
                              void* d_out, int out_size, void* d_ws, size_t ws_size,
                              hipStream_t stream) {
    const float* x     = (const float*)d_in[0];
    const float* W_in  = (const float*)d_in[1];
    const float* b_in  = (const float*)d_in[2];
    const float* W_f   = (const float*)d_in[3];
    const float* b_f   = (const float*)d_in[4];
    const float* W_g   = (const float*)d_in[5];
    const float* b_g   = (const float*)d_in[6];
    const float* W_s   = (const float*)d_in[7];
    const float* b_s   = (const float*)d_in[8];
    const float* W_o   = (const float*)d_in[9];
    const float* b_o   = (const float*)d_in[10];
    const float* W_sk1 = (const float*)d_in[11];
    const float* b_sk1 = (const float*)d_in[12];
    const float* W_sk2 = (const float*)d_in[13];
    const float* b_sk2 = (const float*)d_in[14];
    float* outp = (float*)d_out;

    float* streams = (float*)d_ws;                 // 15*BT floats (30 MB)
    float* fw      = streams + (size_t)15 * BT;    // FW_ALL floats (~172 KB)

    int prep_items = 576 + L_N * RC * SC + SC * SC;
    prep_kernel<<<(prep_items + 255) / 256, 256, 0, stream>>>(
        W_f, W_g, W_in, b_in, b_f, b_g, b_s, W_s, W_sk1, fw);
    pass1_kernel<<<B_N * (T_LEN / C1), NT1, 0, stream>>>(x, fw, W_o, b_o, streams);
    pass2_kernel<<<B_N * (T_LEN / TS), 256, 0, stream>>>(x, streams, fw,
                                                         b_sk1, W_sk2, b_sk2, outp);
}

// Round 4
// 643.996 us; speedup vs baseline: 4.6099x; 1.5656x over previous
//
#include <hip/hip_runtime.h>
#include <math.h>

#define T_LEN 65536
#define B_N   8
#define BT    (T_LEN * B_N)
#define L_N   16
#define RC    32
#define SC    64

// pass1 tiling
#define C1    1024
#define HALO  1020
#define BUFSZ 2048
#define NT1   512

// pass2 tiling
#define TS    128

// folded-weight array offsets (per layer, 12 arrays of 32)
#define A_AF0 0
#define A_AF1 32
#define A_AF2 64
#define A_CF0 96
#define A_CF1 128
#define A_BFC 160
#define A_AG0 192
#define A_AG1 224
#define A_AG2 256
#define A_CG0 288
#define A_CG1 320
#define A_BGC 352
#define FW_L  384
#define FW_BSUM 6144         // +64
#define FW_F32  6208         // float count; bf16 tables follow as shorts
#define WSBF_N  (L_N * SC * RC)   // 32768 shorts
#define W1BF_N  (SC * SC)         // 4096 shorts

typedef float v2f __attribute__((ext_vector_type(2)));
typedef __attribute__((ext_vector_type(4))) float f4;
typedef __attribute__((ext_vector_type(8))) short bf8;

#define MFMA16(a, b, c) __builtin_amdgcn_mfma_f32_16x16x32_bf16(a, b, c, 0, 0, 0)

__device__ __forceinline__ float fast_rcp(float x) { return __builtin_amdgcn_rcpf(x); }

__device__ __forceinline__ float gated_fn(float fp, float gp) {
    float E = __expf(2.f * fp);
    float F = __expf(gp);
    return (E - 1.f) * F * fast_rcp((E + 1.f) * (F + 1.f));
}

// f32 -> bf16 round-to-nearest-even (values finite; no NaN handling needed)
__device__ __forceinline__ unsigned short f2bf(float f) {
    unsigned u = __float_as_uint(f);
    u += 0x7fffu + ((u >> 16) & 1u);
    return (unsigned short)(u >> 16);
}

// ---------------------------------------------------------------------------
// prep: fold gate weights; Bsum; convert W_s / W_sk1 to bf16 tables.
// ---------------------------------------------------------------------------
__global__ __launch_bounds__(256) void prep_kernel(
    const float* __restrict__ W_f, const float* __restrict__ W_g,
    const float* __restrict__ W_in, const float* __restrict__ b_in,
    const float* __restrict__ b_f, const float* __restrict__ b_g,
    const float* __restrict__ b_s, const float* __restrict__ W_s,
    const float* __restrict__ W_sk1, float* __restrict__ fw,
    short* __restrict__ fwh)
{
    int idx = blockIdx.x * 256 + threadIdx.x;
    if (idx < L_N * RC) {
        int i = idx >> 5, c = idx & 31;
        float af[3] = {0,0,0}, cf[3] = {0,0,0}, ag[3] = {0,0,0}, cg[3] = {0,0,0};
        for (int cin = 0; cin < RC; ++cin) {
            float wi = W_in[i * RC + cin];
            float bi = b_in[i * RC + cin];
            #pragma unroll
            for (int k = 0; k < 3; ++k) {
                float wf = W_f[((i * RC + c) * RC + cin) * 3 + k];
                float wg = W_g[((i * RC + c) * RC + cin) * 3 + k];
                af[k] = fmaf(wf, wi, af[k]);
                cf[k] = fmaf(wf, bi, cf[k]);
                ag[k] = fmaf(wg, wi, ag[k]);
                cg[k] = fmaf(wg, bi, cg[k]);
            }
        }
        float* p = fw + i * FW_L;
        p[A_AF0 + c] = af[0]; p[A_AF1 + c] = af[1]; p[A_AF2 + c] = af[2];
        p[A_CF0 + c] = cf[0]; p[A_CF1 + c] = cf[1];
        p[A_BFC + c] = b_f[i * RC + c] + cf[2];
        p[A_AG0 + c] = ag[0]; p[A_AG1 + c] = ag[1]; p[A_AG2 + c] = ag[2];
        p[A_CG0 + c] = cg[0]; p[A_CG1 + c] = cg[1];
        p[A_BGC + c] = b_g[i * RC + c] + cg[2];
    } else if (idx < L_N * RC + SC) {
        int s = idx - L_N * RC;
        float acc = 0.f;
        for (int i = 0; i < L_N; ++i) acc += b_s[i * SC + s];
        fw[FW_BSUM + s] = acc;
    } else if (idx < 576 + WSBF_N) {
        int j = idx - 576;
        fwh[j] = (short)f2bf(W_s[j]);            // layout [i][s][k] == W_s flat
    } else if (idx < 576 + WSBF_N + W1BF_N) {
        int j = idx - 576 - WSBF_N;
        fwh[WSBF_N + j] = (short)f2bf(W_sk1[j]); // layout [o][s] == W_sk1 flat
    }
}

// ---------------------------------------------------------------------------
// pass1: scalar streams out_1..out_15 (inputs of layers 1..15). 512 threads.
// ---------------------------------------------------------------------------
__global__ __launch_bounds__(NT1) void pass1_kernel(
    const float* __restrict__ x, const float* __restrict__ fw,
    const float* __restrict__ W_o, const float* __restrict__ b_o,
    float* __restrict__ streams)
{
    __shared__ __align__(16) float buf[2][BUFSZ];
    __shared__ __align__(16) float sGW[FW_L];
    __shared__ __align__(16) float lwo[32];
    __shared__ float lbo[1];

    int b     = blockIdx.x >> 6;
    int chunk = blockIdx.x & 63;
    int t0    = chunk * C1;
    const float* xb = x + (size_t)b * T_LEN;
    int tid = threadIdx.x;

    for (int p = tid; p < C1 + HALO; p += NT1) {
        int t = t0 - HALO + p;
        buf[0][p] = (t >= 0) ? xb[t] : 0.f;
    }

    int cur = 0;
    int rem = HALO;
    for (int i = 0; i < 15; ++i) {
        int d    = 1 << (i & 7);
        int remN = rem - 2 * d;
        __syncthreads();
        if (tid < FW_L) sGW[tid] = fw[i * FW_L + tid];
        if (tid >= FW_L && tid < FW_L + 32) lwo[tid - FW_L] = W_o[i * 32 + (tid - FW_L)];
        if (tid == FW_L + 32) lbo[0] = b_o[i];
        __syncthreads();

        int lo  = HALO - remN;
        int nxt = cur ^ 1;

        v2f s0p[2], s1p[2], s2p[2], accp[2], m0p[2], m1p[2];
        bool on[4];
        #pragma unroll
        for (int j = 0; j < 4; ++j) {
            int p = lo + tid + j * NT1;
            int t = t0 - HALO + p;
            bool inr = (p < C1 + HALO);
            on[j]  = inr && (t >= 0);
            int jp = j >> 1, e = j & 1;
            float v2 = 0.f, v1 = 0.f, v0 = 0.f;
            if (inr) {
                v2 = buf[cur][p];
                v1 = buf[cur][p - d];
                v0 = buf[cur][p - 2 * d];
            }
            if (e == 0) {
                s2p[jp].x = v2; s1p[jp].x = v1; s0p[jp].x = v0;
                accp[jp].x = 0.f;
                m1p[jp].x = (t - d     >= 0) ? 1.f : 0.f;
                m0p[jp].x = (t - 2 * d >= 0) ? 1.f : 0.f;
            } else {
                s2p[jp].y = v2; s1p[jp].y = v1; s0p[jp].y = v0;
                accp[jp].y = 0.f;
                m1p[jp].y = (t - d     >= 0) ? 1.f : 0.f;
                m0p[jp].y = (t - 2 * d >= 0) ? 1.f : 0.f;
            }
        }

        const f4* g4 = (const f4*)sGW;
        const f4* w4 = (const f4*)lwo;
        for (int c4 = 0; c4 < 8; ++c4) {
            f4 vaf0 = g4[(A_AF0 >> 2) + c4], vaf1 = g4[(A_AF1 >> 2) + c4], vaf2 = g4[(A_AF2 >> 2) + c4];
            f4 vcf0 = g4[(A_CF0 >> 2) + c4], vcf1 = g4[(A_CF1 >> 2) + c4], vbfc = g4[(A_BFC >> 2) + c4];
            f4 vag0 = g4[(A_AG0 >> 2) + c4], vag1 = g4[(A_AG1 >> 2) + c4], vag2 = g4[(A_AG2 >> 2) + c4];
            f4 vcg0 = g4[(A_CG0 >> 2) + c4], vcg1 = g4[(A_CG1 >> 2) + c4], vbgc = g4[(A_BGC >> 2) + c4];
            f4 vwo  = w4[c4];
            #pragma unroll
            for (int e = 0; e < 4; ++e) {
                float af0 = vaf0[e], af1 = vaf1[e], af2 = vaf2[e];
                float cf0 = vcf0[e], cf1 = vcf1[e], bfc = vbfc[e];
                float ag0 = vag0[e], ag1 = vag1[e], ag2 = vag2[e];
                float cg0 = vcg0[e], cg1 = vcg1[e], bgc = vbgc[e];
                float woc = vwo[e];
                #pragma unroll
                for (int jp = 0; jp < 2; ++jp) {
                    v2f fp = (v2f){bfc, bfc} + m0p[jp] * (v2f){cf0, cf0} + m1p[jp] * (v2f){cf1, cf1};
                    fp = fp + s0p[jp] * (v2f){af0, af0} + s1p[jp] * (v2f){af1, af1} + s2p[jp] * (v2f){af2, af2};
                    v2f gp = (v2f){bgc, bgc} + m0p[jp] * (v2f){cg0, cg0} + m1p[jp] * (v2f){cg1, cg1};
                    gp = gp + s0p[jp] * (v2f){ag0, ag0} + s1p[jp] * (v2f){ag1, ag1} + s2p[jp] * (v2f){ag2, ag2};
                    v2f g;
                    g.x = gated_fn(fp.x, gp.x);
                    g.y = gated_fn(fp.y, gp.y);
                    accp[jp] = accp[jp] + g * (v2f){woc, woc};
                }
            }
        }

        float s2a[4]  = {s2p[0].x, s2p[0].y, s2p[1].x, s2p[1].y};
        float acca[4] = {accp[0].x, accp[0].y, accp[1].x, accp[1].y};
        #pragma unroll
        for (int j = 0; j < 4; ++j) {
            int p = lo + tid + j * NT1;
            if (p < C1 + HALO) {
                int t = t0 - HALO + p;
                float outv = on[j] ? (s2a[j] + lbo[0] + acca[j]) : 0.f;
                buf[nxt][p] = outv;
                if (p >= HALO)
                    streams[(size_t)i * BT + (size_t)b * T_LEN + t] = outv;
            }
        }
        cur = nxt;
        rem = remN;
    }
}

// ---------------------------------------------------------------------------
// pass2: MFMA skip-GEMM. Block = 128 t, 4 waves. Per layer: gate phase
// (4t x 4ch per thread) writes bf16 G[t][k] (stride 40 bf16 = 80 B) in MFMA
// A-layout; MFMA phase: wave w owns t-tiles {2w,2w+1} x 4 s-tiles, B-frags
// (bf16 W_s) straight from global. Head = second MFMA GEMM (K=64) via bf16
// skip round-trip in LDS (stride 72 bf16 = 144 B), shfl-reduce epilogue.
// ---------------------------------------------------------------------------
#define SMB_G    0        // layer: 128 rows x 80 B (10240); head: 128 x 144 B (18432)
#define SMB_TAP  18432    // 3 x 128 f32 = 1536 B
#define SMB_MISC 19968    // bsum[64] b1[64] w2[128] b2[2] = 1032 B
#define SMB_TOT  21504

__global__ __launch_bounds__(256) void pass2_kernel(
    const float* __restrict__ x, const float* __restrict__ streams,
    const float* __restrict__ fw, const short* __restrict__ Wsbf,
    const short* __restrict__ W1bf, const float* __restrict__ b_sk1,
    const float* __restrict__ W_sk2, const float* __restrict__ b_sk2,
    float* __restrict__ out)
{
    __shared__ __align__(16) char smb[SMB_TOT];
    float* sTap  = (float*)(smb + SMB_TAP);
    float* sMisc = (float*)(smb + SMB_MISC);

    int tid   = threadIdx.x;
    int b     = blockIdx.x >> 9;
    int chunk = blockIdx.x & 511;
    int t0    = chunk * TS;

    if (tid < 64) { sMisc[tid] = fw[FW_BSUM + tid]; sMisc[64 + tid] = b_sk1[tid]; }
    if (tid < 128) sMisc[128 + tid] = W_sk2[tid];
    if (tid < 2)   sMisc[256 + tid] = b_sk2[tid];

    int wv   = tid >> 6;
    int lane = tid & 63;
    int m    = lane & 15;         // MFMA row/col-in-tile
    int q    = lane >> 4;         // MFMA quad
    int tq   = tid >> 3;          // gate: t-quad 0..31
    int cq   = tid & 7;           // gate: channel-quad 0..7

    f4 zero4 = {0.f, 0.f, 0.f, 0.f};
    f4 acc[2][4];
    #pragma unroll
    for (int tt = 0; tt < 2; ++tt)
        #pragma unroll
        for (int st = 0; st < 4; ++st) acc[tt][st] = zero4;

    for (int i = 0; i < L_N; ++i) {
        int d = 1 << (i & 7);
        const float* src = (i == 0) ? (x + (size_t)b * T_LEN)
                                    : (streams + (size_t)(i - 1) * BT + (size_t)b * T_LEN);

        // B-fragments (bf16 W_s) straight from global; reused over 2 t-tiles
        bf8 bfrag[4];
        #pragma unroll
        for (int st = 0; st < 4; ++st)
            bfrag[st] = *(const bf8*)(Wsbf + i * (SC * RC) + (st * 16 + m) * RC + q * 8);

        // gate weights from global (L1-broadcast), indexed by this thread's cq
        const float* gw = fw + i * FW_L + cq * 4;
        f4 af0 = *(const f4*)(gw + A_AF0), af1 = *(const f4*)(gw + A_AF1), af2 = *(const f4*)(gw + A_AF2);
        f4 cf0 = *(const f4*)(gw + A_CF0), cf1 = *(const f4*)(gw + A_CF1), bfc = *(const f4*)(gw + A_BFC);
        f4 ag0 = *(const f4*)(gw + A_AG0), ag1 = *(const f4*)(gw + A_AG1), ag2 = *(const f4*)(gw + A_AG2);
        f4 cg0 = *(const f4*)(gw + A_CG0), cg1 = *(const f4*)(gw + A_CG1), bgc = *(const f4*)(gw + A_BGC);

        __syncthreads();   // prev layer's A-frag reads done; taps consumable
        // stage taps (zero-masked)
        for (int j = tid; j < 3 * TS; j += 256) {
            int a = j >> 7, p = j & (TS - 1);
            int t = t0 + p - a * d;
            sTap[j] = (t >= 0) ? src[t] : 0.f;
        }
        __syncthreads();   // taps ready

        // ---- gate phase: 4 t x 4 ch per thread ----
        {
            f4 s2q = *(const f4*)(sTap + tq * 4);
            f4 s1q = *(const f4*)(sTap + TS + tq * 4);
            f4 s0q = *(const f4*)(sTap + 2 * TS + tq * 4);
            #pragma unroll
            for (int j = 0; j < 4; ++j) {
                int t = t0 + tq * 4 + j;
                float m1 = (t >= d)     ? 1.f : 0.f;
                float m0 = (t >= 2 * d) ? 1.f : 0.f;
                f4 fp = bfc + m0 * cf0 + m1 * cf1 + s0q[j] * af0 + s1q[j] * af1 + s2q[j] * af2;
                f4 gp = bgc + m0 * cg0 + m1 * cg1 + s0q[j] * ag0 + s1q[j] * ag1 + s2q[j] * ag2;
                ushort4 gv;
                gv.x = f2bf(gated_fn(fp[0], gp[0]));
                gv.y = f2bf(gated_fn(fp[1], gp[1]));
                gv.z = f2bf(gated_fn(fp[2], gp[2]));
                gv.w = f2bf(gated_fn(fp[3], gp[3]));
                *(ushort4*)(smb + (tq * 4 + j) * 80 + cq * 8) = gv;
            }
        }
        __syncthreads();   // G ready

        // ---- MFMA phase ----
        #pragma unroll
        for (int tt = 0; tt < 2; ++tt) {
            int trow = (wv * 2 + tt) * 16 + m;
            bf8 afrag = *(const bf8*)(smb + trow * 80 + q * 16);
            #pragma unroll
            for (int st = 0; st < 4; ++st)
                acc[tt][st] = MFMA16(afrag, bfrag[st], acc[tt][st]);
        }
    }

    // ---- head ----
    __syncthreads();   // all waves' last A-frag reads done; G region reusable
    // skip (+Bsum) -> bf16 LDS [t][s], stride 144 B
    #pragma unroll
    for (int tt = 0; tt < 2; ++tt) {
        int tb = (wv * 2 + tt) * 16 + q * 4;
        #pragma unroll
        for (int st = 0; st < 4; ++st) {
            int s = st * 16 + m;
            float bs = sMisc[s];
            #pragma unroll
            for (int r = 0; r < 4; ++r)
                *(unsigned short*)(smb + (tb + r) * 144 + s * 2) = f2bf(acc[tt][st][r] + bs);
        }
    }
    // W1 B-fragments from global bf16 [o][s]
    bf8 w1f[4][2];
    #pragma unroll
    for (int ot = 0; ot < 4; ++ot)
        #pragma unroll
        for (int kc = 0; kc < 2; ++kc)
            w1f[ot][kc] = *(const bf8*)(W1bf + (ot * 16 + m) * SC + kc * 32 + q * 8);
    __syncthreads();   // skip matrix ready

    f4 hacc[2][4];
    #pragma unroll
    for (int tt = 0; tt < 2; ++tt)
        #pragma unroll
        for (int ot = 0; ot < 4; ++ot) hacc[tt][ot] = zero4;
    #pragma unroll
    for (int tt = 0; tt < 2; ++tt) {
        int trow = (wv * 2 + tt) * 16 + m;
        #pragma unroll
        for (int kc = 0; kc < 2; ++kc) {
            bf8 afrag = *(const bf8*)(smb + trow * 144 + kc * 64 + q * 16);
            #pragma unroll
            for (int ot = 0; ot < 4; ++ot)
                hacc[tt][ot] = MFMA16(afrag, w1f[ot][kc], hacc[tt][ot]);
        }
    }

    // epilogue: relu + W_sk2 contraction + cross-lane reduce over o (col bits)
    float p0[2][4], p1[2][4];
    #pragma unroll
    for (int tt = 0; tt < 2; ++tt)
        #pragma unroll
        for (int r = 0; r < 4; ++r) { p0[tt][r] = 0.f; p1[tt][r] = 0.f; }
    #pragma unroll
    for (int ot = 0; ot < 4; ++ot) {
        int o = ot * 16 + m;
        float w20 = sMisc[128 + o], w21 = sMisc[192 + o], b1v = sMisc[64 + o];
        #pragma unroll
        for (int tt = 0; tt < 2; ++tt)
            #pragma unroll
            for (int r = 0; r < 4; ++r) {
                float hv = fmaxf(hacc[tt][ot][r] + b1v, 0.f);
                p0[tt][r] = fmaf(w20, hv, p0[tt][r]);
                p1[tt][r] = fmaf(w21, hv, p1[tt][r]);
            }
    }
    #pragma unroll
    for (int msk = 1; msk <= 8; msk <<= 1) {
        #pragma unroll
        for (int tt = 0; tt < 2; ++tt)
            #pragma unroll
            for (int r = 0; r < 4; ++r) {
                p0[tt][r] += __shfl_xor(p0[tt][r], msk);
                p1[tt][r] += __shfl_xor(p1[tt][r], msk);
            }
    }
    if (m == 0) {
        float b20 = sMisc[256], b21 = sMisc[257];
        #pragma unroll
        for (int tt = 0; tt < 2; ++tt) {
            int t = t0 + (wv * 2 + tt) * 16 + q * 4;
            size_t gi = (size_t)b * T_LEN + t;
            f4 mv, sv;
            #pragma unroll
            for (int r = 0; r < 4; ++r) {
                mv[r] = p0[tt][r] + b20;
                sv[r] = __expf(0.5f * (p1[tt][r] + b21));
            }
            *(f4*)(out + gi)      = mv;
            *(f4*)(out + BT + gi) = sv;
        }
    }
}

// ---------------------------------------------------------------------------
extern "C" void kernel_launch(void* const* d_in, const int* in_sizes, int n_in,
                              void* d_out, int out_size, void* d_ws, size_t ws_size,
                              hipStream_t stream) {
    const float* x     = (const float*)d_in[0];
    const float* W_in  = (const float*)d_in[1];
    const float* b_in  = (const float*)d_in[2];
    const float* W_f   = (const float*)d_in[3];
    const float* b_f   = (const float*)d_in[4];
    const float* W_g   = (const float*)d_in[5];
    const float* b_g   = (const float*)d_in[6];
    const float* W_s   = (const float*)d_in[7];
    const float* b_s   = (const float*)d_in[8];
    const float* W_o   = (const float*)d_in[9];
    const float* b_o   = (const float*)d_in[10];
    const float* W_sk1 = (const float*)d_in[11];
    const float* b_sk1 = (const float*)d_in[12];
    const float* W_sk2 = (const float*)d_in[13];
    const float* b_sk2 = (const float*)d_in[14];
    float* outp = (float*)d_out;

    float* streams = (float*)d_ws;                 // 15*BT floats (30 MB)
    float* fw      = streams + (size_t)15 * BT;    // FW_F32 floats
    short* fwh     = (short*)(fw + FW_F32);        // bf16 tables

    int prep_items = 576 + WSBF_N + W1BF_N;
    prep_kernel<<<(prep_items + 255) / 256, 256, 0, stream>>>(
        W_f, W_g, W_in, b_in, b_f, b_g, b_s, W_s, W_sk1, fw, fwh);
    pass1_kernel<<<B_N * (T_LEN / C1), NT1, 0, stream>>>(x, fw, W_o, b_o, streams);
    pass2_kernel<<<B_N * (T_LEN / TS), 256, 0, stream>>>(
        x, streams, fw, fwh, fwh + WSBF_N, b_sk1, W_sk2, b_sk2, outp);
}